// Round 3
// baseline (176.738 us; speedup 1.0000x reference)
//
#include <hip/hip_runtime.h>

#define COORD 5.0f
#define NO_OBJ 0.5f
#define NCELLS (8192 * 49)
#define INV_B (1.0f / 8192.0f)

// One wave (64 lanes) per block; each block owns 64 cells = 1920 floats/array.
// Stage via global_load_lds DMA (no VGPR round-trip): per array per lane,
// 7x dwordx4 (448 float4) + 2x dword (tail 128 floats) = 1920 floats/wave.

#define GLD(gaddr, laddr, sz)                                                        \
    __builtin_amdgcn_global_load_lds(                                                \
        (const __attribute__((address_space(1))) void*)(gaddr),                      \
        (__attribute__((address_space(3))) void*)(laddr), (sz), 0, 0)

__device__ __forceinline__ float iou_calc(float ax1, float ay1, float ax2, float ay2,
                                          float bx1, float by1, float bx2, float by2) {
    float iw = fminf(ax2, bx2) - fmaxf(ax1, bx1);
    iw = fmaxf(iw, 0.0f);
    float ih = fminf(ay2, by2) - fmaxf(ay1, by1);
    ih = fmaxf(ih, 0.0f);
    float inter = iw * ih;
    float area_a = (ax2 - ax1) * (ay2 - ay1);
    float area_b = (bx2 - bx1) * (by2 - by1);
    float uni = area_a + area_b - inter;
    return uni > 0.0f ? inter / uni : 0.0f;
}

__global__ __launch_bounds__(64) void yolo_loss_kernel(
    const float* __restrict__ data, const float* __restrict__ labels,
    float* __restrict__ out) {
    __shared__ float sd[1920];
    __shared__ float sl[1920];

    const int ln = threadIdx.x;  // 0..63
    const size_t fbase = (size_t)blockIdx.x * 1920;  // float index; byte ofs 7680B, 16B-aligned

    const float4* gd4 = (const float4*)(data + fbase);
    const float4* gl4 = (const float4*)(labels + fbase);
    float4* sd4 = (float4*)sd;
    float4* sl4 = (float4*)sl;
#pragma unroll
    for (int j = 0; j < 7; j++) {
        GLD(gd4 + j * 64 + ln, sd4 + j * 64 + ln, 16);
        GLD(gl4 + j * 64 + ln, sl4 + j * 64 + ln, 16);
    }
#pragma unroll
    for (int k = 0; k < 2; k++) {
        GLD(data + fbase + 1792 + k * 64 + ln, sd + 1792 + k * 64 + ln, 4);
        GLD(labels + fbase + 1792 + k * 64 + ln, sl + 1792 + k * 64 + ln, 4);
    }
    __syncthreads();  // single-wave block: emits vmcnt(0) drain + cheap barrier

    // Per-cell gather from LDS (stride 30 floats, 8B-aligned -> float2 reads).
    const int idx = blockIdx.x * 64 + ln;
    const int cell = idx % 49;
    const float r = (float)(cell / 7);
    const float c = (float)(cell % 7);

    float d[30], l[30];
    const float2* dp = (const float2*)(sd + ln * 30);
    const float2* lp = (const float2*)(sl + ln * 30);
#pragma unroll
    for (int i = 0; i < 15; i++) {
        float2 v = dp[i];
        d[2 * i] = v.x; d[2 * i + 1] = v.y;
        float2 w2 = lp[i];
        l[2 * i] = w2.x; l[2 * i + 1] = w2.y;
    }

    const float inv_g = 1.0f / 7.0f;
    float cx1 = (d[0] + c) * inv_g, cy1 = (d[1] + r) * inv_g;
    float b1x1 = cx1 - d[2] * 0.5f, b1y1 = cy1 - d[3] * 0.5f;
    float b1x2 = cx1 + d[2] * 0.5f, b1y2 = cy1 + d[3] * 0.5f;
    float cx2 = (d[5] + c) * inv_g, cy2 = (d[6] + r) * inv_g;
    float b2x1 = cx2 - d[7] * 0.5f, b2y1 = cy2 - d[8] * 0.5f;
    float b2x2 = cx2 + d[7] * 0.5f, b2y2 = cy2 + d[8] * 0.5f;
    float gx = (l[0] + c) * inv_g, gy = (l[1] + r) * inv_g;
    float gx1 = gx - l[2] * 0.5f, gy1 = gy - l[3] * 0.5f;
    float gx2 = gx + l[2] * 0.5f, gy2 = gy + l[3] * 0.5f;

    float iou1 = iou_calc(b1x1, b1y1, b1x2, b1y2, gx1, gy1, gx2, gy2);
    float iou2 = iou_calc(b2x1, b2y1, b2x2, b2y2, gx1, gy1, gx2, gy2);
    bool resp1 = iou1 >= iou2;

    float xy1 = (d[0] - l[0]) * (d[0] - l[0]) + (d[1] - l[1]) * (d[1] - l[1]);
    float xy2 = (d[5] - l[5]) * (d[5] - l[5]) + (d[6] - l[6]) * (d[6] - l[6]);
    float s2 = sqrtf(d[2]) - sqrtf(l[2]);
    float s3 = sqrtf(d[3]) - sqrtf(l[3]);
    float wh1 = s2 * s2 + s3 * s3;
    float s7 = sqrtf(d[7]) - sqrtf(l[7]);
    float s8 = sqrtf(d[8]) - sqrtf(l[8]);
    float wh2 = s7 * s7 + s8 * s8;

    float d4 = d[4], d9 = d[9];
    float co = COORD * (resp1 ? xy1 : xy2);
    float wh = COORD * (resp1 ? wh1 : wh2);
    float ci = resp1 ? (d4 - iou1) * (d4 - iou1) : (d9 - iou2) * (d9 - iou2);
    float noobj_in = NO_OBJ * (resp1 ? d9 * d9 : d4 * d4);
    float cls = 0.0f;
#pragma unroll
    for (int i = 10; i < 30; i++) {
        float t = d[i] - l[i];
        cls += t * t;
    }

    float loss = (l[4] == 1.0f)
                     ? (co + wh + ci + noobj_in + cls)
                     : NO_OBJ * (d4 * d4 + d9 * d9);
    float acc = loss * INV_B;

    // wave (64-lane) reduction, then one atomic per block
#pragma unroll
    for (int off = 32; off > 0; off >>= 1)
        acc += __shfl_down(acc, off, 64);
    if (ln == 0) atomicAdd(out, acc);
}

extern "C" void kernel_launch(void* const* d_in, const int* in_sizes, int n_in,
                              void* d_out, int out_size, void* d_ws, size_t ws_size,
                              hipStream_t stream) {
    const float* data = (const float*)d_in[0];
    const float* labels = (const float*)d_in[1];
    float* out = (float*)d_out;

    hipMemsetAsync(out, 0, sizeof(float) * out_size, stream);

    int nblocks = NCELLS / 64;  // 401408 / 64 = 6272, exact
    yolo_loss_kernel<<<nblocks, 64, 0, stream>>>(data, labels, out);
}

// Round 4
// 112.894 us; speedup vs baseline: 1.5655x; 1.5655x over previous
//
#include <hip/hip_runtime.h>

#define COORD 5.0f
#define NO_OBJ 0.5f
#define NCELLS (8192 * 49)
#define INV_B (1.0f / 8192.0f)

#define CPB 128                      // cells per block = threads per block
#define FPB (CPB * 30)               // floats per block per array = 3840
#define NBLK (NCELLS / CPB)          // 3136

__device__ __forceinline__ float iou_calc(float ax1, float ay1, float ax2, float ay2,
                                          float bx1, float by1, float bx2, float by2) {
    float iw = fminf(ax2, bx2) - fmaxf(ax1, bx1);
    iw = fmaxf(iw, 0.0f);
    float ih = fminf(ay2, by2) - fmaxf(ay1, by1);
    ih = fmaxf(ih, 0.0f);
    float inter = iw * ih;
    float area_a = (ax2 - ax1) * (ay2 - ay1);
    float area_b = (bx2 - bx1) * (by2 - by1);
    float uni = area_a + area_b - inter;
    return uni > 0.0f ? inter / uni : 0.0f;
}

// 30.7 KB LDS/block -> 5 blocks/CU resident; independent phases keep HBM busy.
__global__ __launch_bounds__(128) void yolo_loss_kernel(
    const float* __restrict__ data, const float* __restrict__ labels,
    float* __restrict__ ws) {
    __shared__ float sd[FPB];
    __shared__ float sl[FPB];

    const int tid = threadIdx.x;
    const size_t fbase = (size_t)blockIdx.x * FPB;  // 15360 B/block, 16B-aligned

    // Coalesced staging: 960 float4 per array = 7 full rounds + 128 float2 tail.
    const float4* gd4 = (const float4*)(data + fbase);
    const float4* gl4 = (const float4*)(labels + fbase);
    float4* sd4 = (float4*)sd;
    float4* sl4 = (float4*)sl;
#pragma unroll
    for (int j = 0; j < 7; j++) {
        sd4[j * 128 + tid] = gd4[j * 128 + tid];
        sl4[j * 128 + tid] = gl4[j * 128 + tid];
    }
    {
        const float2* gd2 = (const float2*)(data + fbase + 3584);
        const float2* gl2 = (const float2*)(labels + fbase + 3584);
        ((float2*)(sd + 3584))[tid] = gd2[tid];
        ((float2*)(sl + 3584))[tid] = gl2[tid];
    }
    __syncthreads();

    // Per-cell gather from LDS (stride-30 floats -> 4-way bank conflict, cheap).
    const int idx = blockIdx.x * CPB + tid;
    const int cell = idx % 49;
    const float r = (float)(cell / 7);
    const float c = (float)(cell % 7);

    float d[30], l[30];
    const float2* dp = (const float2*)(sd + tid * 30);
    const float2* lp = (const float2*)(sl + tid * 30);
#pragma unroll
    for (int i = 0; i < 15; i++) {
        float2 v = dp[i];
        d[2 * i] = v.x; d[2 * i + 1] = v.y;
        float2 w2 = lp[i];
        l[2 * i] = w2.x; l[2 * i + 1] = w2.y;
    }

    const float inv_g = 1.0f / 7.0f;
    float cx1 = (d[0] + c) * inv_g, cy1 = (d[1] + r) * inv_g;
    float b1x1 = cx1 - d[2] * 0.5f, b1y1 = cy1 - d[3] * 0.5f;
    float b1x2 = cx1 + d[2] * 0.5f, b1y2 = cy1 + d[3] * 0.5f;
    float cx2 = (d[5] + c) * inv_g, cy2 = (d[6] + r) * inv_g;
    float b2x1 = cx2 - d[7] * 0.5f, b2y1 = cy2 - d[8] * 0.5f;
    float b2x2 = cx2 + d[7] * 0.5f, b2y2 = cy2 + d[8] * 0.5f;
    float gx = (l[0] + c) * inv_g, gy = (l[1] + r) * inv_g;
    float gx1 = gx - l[2] * 0.5f, gy1 = gy - l[3] * 0.5f;
    float gx2 = gx + l[2] * 0.5f, gy2 = gy + l[3] * 0.5f;

    float iou1 = iou_calc(b1x1, b1y1, b1x2, b1y2, gx1, gy1, gx2, gy2);
    float iou2 = iou_calc(b2x1, b2y1, b2x2, b2y2, gx1, gy1, gx2, gy2);
    bool resp1 = iou1 >= iou2;

    float xy1 = (d[0] - l[0]) * (d[0] - l[0]) + (d[1] - l[1]) * (d[1] - l[1]);
    float xy2 = (d[5] - l[5]) * (d[5] - l[5]) + (d[6] - l[6]) * (d[6] - l[6]);
    float s2 = sqrtf(d[2]) - sqrtf(l[2]);
    float s3 = sqrtf(d[3]) - sqrtf(l[3]);
    float wh1 = s2 * s2 + s3 * s3;
    float s7 = sqrtf(d[7]) - sqrtf(l[7]);
    float s8 = sqrtf(d[8]) - sqrtf(l[8]);
    float wh2 = s7 * s7 + s8 * s8;

    float d4 = d[4], d9 = d[9];
    float co = COORD * (resp1 ? xy1 : xy2);
    float wh = COORD * (resp1 ? wh1 : wh2);
    float ci = resp1 ? (d4 - iou1) * (d4 - iou1) : (d9 - iou2) * (d9 - iou2);
    float noobj_in = NO_OBJ * (resp1 ? d9 * d9 : d4 * d4);
    float cls = 0.0f;
#pragma unroll
    for (int i = 10; i < 30; i++) {
        float t = d[i] - l[i];
        cls += t * t;
    }

    float loss = (l[4] == 1.0f)
                     ? (co + wh + ci + noobj_in + cls)
                     : NO_OBJ * (d4 * d4 + d9 * d9);
    float acc = loss * INV_B;

    // wave reduction -> per-block partial into ws[blockIdx] (no atomic contention)
#pragma unroll
    for (int off = 32; off > 0; off >>= 1)
        acc += __shfl_down(acc, off, 64);

    __shared__ float wsum[2];
    if ((tid & 63) == 0) wsum[tid >> 6] = acc;
    __syncthreads();
    if (tid == 0) ws[blockIdx.x] = wsum[0] + wsum[1];
}

__global__ __launch_bounds__(256) void reduce_kernel(const float* __restrict__ ws,
                                                     float* __restrict__ out) {
    float s = 0.0f;
    for (int i = threadIdx.x; i < NBLK; i += 256) s += ws[i];
#pragma unroll
    for (int off = 32; off > 0; off >>= 1)
        s += __shfl_down(s, off, 64);
    __shared__ float w[4];
    if ((threadIdx.x & 63) == 0) w[threadIdx.x >> 6] = s;
    __syncthreads();
    if (threadIdx.x == 0) out[0] = w[0] + w[1] + w[2] + w[3];
}

extern "C" void kernel_launch(void* const* d_in, const int* in_sizes, int n_in,
                              void* d_out, int out_size, void* d_ws, size_t ws_size,
                              hipStream_t stream) {
    const float* data = (const float*)d_in[0];
    const float* labels = (const float*)d_in[1];
    float* out = (float*)d_out;
    float* ws = (float*)d_ws;  // NBLK floats of scratch

    yolo_loss_kernel<<<NBLK, CPB, 0, stream>>>(data, labels, ws);
    reduce_kernel<<<1, 256, 0, stream>>>(ws, out);
}